// Round 7
// baseline (1157.226 us; speedup 1.0000x reference)
//
#include <hip/hip_runtime.h>
#include <hip/hip_bf16.h>
#include <math.h>

#define K 4
#define F 513
#define B 4000
#define NIT 5
#define FB (F*B)
#define FCH 65        // ceil(513/8) f-chunk for demix/final
#define NFC 8

// ---------------- persistent scratch: static device globals (all fp64) ------
__device__ double2 g_Wh[F*16];     // (F,4,4) complex
__device__ double2 g_V[64*F];      // (k,i,j,f) complex, k*16+i*4+j major
__device__ double2 g_scale[F*4];   // (F,4) complex
__device__ double  g_r2[K*B];      // (K,B) real

// ---------------- complex double helpers ------------------------------------
struct cd { double re, im; };
__device__ inline cd mkcd(double r, double i){ cd z; z.re=r; z.im=i; return z; }
__device__ inline cd cmul(cd a, cd b){ return mkcd(a.re*b.re - a.im*b.im, a.re*b.im + a.im*b.re); }
__device__ inline cd cadd(cd a, cd b){ return mkcd(a.re+b.re, a.im+b.im); }
__device__ inline cd csub(cd a, cd b){ return mkcd(a.re-b.re, a.im-b.im); }
__device__ inline cd conj_(cd a){ return mkcd(a.re, -a.im); }
__device__ inline cd cdiv(cd a, cd b){
  double d = b.re*b.re + b.im*b.im;
  return mkcd((a.re*b.re + a.im*b.im)/d, (a.im*b.re - a.re*b.im)/d);
}

// Gauss-Jordan solve M x = rhs (x overwritten), partial pivoting.
__device__ void solve4(cd M[4][4], cd x[4]){
  for (int col=0; col<4; ++col){
    int piv = col;
    double best = M[col][col].re*M[col][col].re + M[col][col].im*M[col][col].im;
    for (int r=col+1; r<4; ++r){
      double m = M[r][col].re*M[r][col].re + M[r][col].im*M[r][col].im;
      if (m > best){ best = m; piv = r; }
    }
    if (piv != col){
      for (int cc=0; cc<4; ++cc){ cd t=M[col][cc]; M[col][cc]=M[piv][cc]; M[piv][cc]=t; }
      cd t=x[col]; x[col]=x[piv]; x[piv]=t;
    }
    cd ip = cdiv(mkcd(1.0,0.0), M[col][col]);
    for (int cc=0; cc<4; ++cc) M[col][cc] = cmul(M[col][cc], ip);
    x[col] = cmul(x[col], ip);
    for (int r=0; r<4; ++r){
      if (r == col) continue;
      cd fct = M[r][col];
      for (int cc=0; cc<4; ++cc) M[r][cc] = csub(M[r][cc], cmul(fct, M[col][cc]));
      x[r] = csub(x[r], cmul(fct, x[col]));
    }
  }
}

// ---------------- kernels ---------------------------------------------------

__global__ void init_kernel(){
  int t = blockIdx.x*blockDim.x + threadIdx.x;
  if (t < F*16){
    int sc = t & 15; int s = sc >> 2, c = sc & 3;
    g_Wh[t] = make_double2(s==c ? 1.0 : 0.0, 0.0);
  }
  if (t < K*B) g_r2[t] = 0.0;
}

// r2[k,b] += sum over this block's f-chunk of |Y[k,f,b]|^2, Y = Wh[f] * X[:,f,b]
__global__ __launch_bounds__(256) void demix_r2_kernel(
    const float* __restrict__ Xr, const float* __restrict__ Xi){
  int b = blockIdx.x*blockDim.x + threadIdx.x;
  if (b >= B) return;
  int f0 = blockIdx.y*FCH, f1 = min(f0+FCH, F);
  double acc[K];
  #pragma unroll
  for (int s=0;s<K;++s) acc[s]=0.0;
  for (int f=f0; f<f1; ++f){
    double xr[K], xi[K];
    #pragma unroll
    for (int c=0;c<K;++c){ int idx=c*FB + f*B + b; xr[c]=(double)Xr[idx]; xi[c]=(double)Xi[idx]; }
    const double2* w = g_Wh + f*16;
    #pragma unroll
    for (int s=0;s<K;++s){
      double yr=0.0, yi=0.0;
      #pragma unroll
      for (int c=0;c<K;++c){
        double2 ww = w[s*4+c];
        yr += ww.x*xr[c] - ww.y*xi[c];
        yi += ww.x*xi[c] + ww.y*xr[c];
      }
      acc[s] += yr*yr + yi*yi;
    }
  }
  #pragma unroll
  for (int s=0;s<K;++s) atomicAdd(&g_r2[s*B+b], acc[s]);
}

// V[k,i,j,f] = (1/B) sum_b phi[k,b] X[i,f,b] conj(X[j,f,b]); block = (f, k).
__global__ __launch_bounds__(256) void v_kernel(
    const float* __restrict__ Xr, const float* __restrict__ Xi){
  int f = blockIdx.x;
  int k = blockIdx.y;
  int tid = threadIdx.x;
  double acc[16];
  #pragma unroll
  for (int q=0;q<16;++q) acc[q]=0.0;

  for (int b=tid; b<B; b+=256){
    double phi = 0.5 / sqrt(g_r2[k*B+b]);
    double xr[K], xi[K];
    #pragma unroll
    for (int c=0;c<K;++c){ int idx=c*FB + f*B + b; xr[c]=(double)Xr[idx]; xi[c]=(double)Xi[idx]; }
    double p[16];
    #pragma unroll
    for (int i=0;i<4;++i) p[i] = xr[i]*xr[i] + xi[i]*xi[i];   // diagonals (real)
    int s = 4;
    #pragma unroll
    for (int i=0;i<4;++i){
      #pragma unroll
      for (int j=i+1;j<4;++j){
        p[s++] = xr[i]*xr[j] + xi[i]*xi[j];   // Re(X_i conj(X_j))
        p[s++] = xi[i]*xr[j] - xr[i]*xi[j];   // Im(X_i conj(X_j))
      }
    }
    #pragma unroll
    for (int q=0;q<16;++q) acc[q] += phi*p[q];
  }

  __shared__ double part[4][16];
  __shared__ double red[16];
  int lane = tid & 63, wave = tid >> 6;
  #pragma unroll
  for (int q=0;q<16;++q){
    double v = acc[q];
    for (int off=32; off>0; off>>=1) v += __shfl_down(v, off);
    if (lane == 0) part[wave][q] = v;
  }
  __syncthreads();
  if (tid < 16){
    red[tid] = (part[0][tid] + part[1][tid] + part[2][tid] + part[3][tid]) * (1.0/B);
  }
  __syncthreads();
  if (tid < 16){
    int i = tid >> 2, j = tid & 3;
    double re, im;
    if (i == j){ re = red[i]; im = 0.0; }
    else {
      int a = min(i,j), c2 = max(i,j);
      int pidx = (a==0) ? (c2-1) : ((a==1) ? (c2+1) : 5);  // (0,1)=0 (0,2)=1 (0,3)=2 (1,2)=3 (1,3)=4 (2,3)=5
      re = red[4 + 2*pidx];
      im = red[5 + 2*pidx];
      if (i > j) im = -im;
    }
    g_V[(k*16 + tid)*F + f] = make_double2(re, im);
  }
}

// Per-f IP updates for k=0..3 (sequential), fp64. Also zeroes r2 for next iter.
__global__ void update_kernel(){
  int t = blockIdx.x*blockDim.x + threadIdx.x;
  int stride = gridDim.x*blockDim.x;
  for (int i=t; i<K*B; i+=stride) g_r2[i] = 0.0;
  if (t >= F) return;
  int f = t;
  cd W[4][4];
  #pragma unroll
  for (int s=0;s<4;++s)
    #pragma unroll
    for (int c=0;c<4;++c){ double2 w = g_Wh[f*16+s*4+c]; W[s][c] = mkcd(w.x, w.y); }

  for (int k=0;k<4;++k){
    cd Vk[4][4];
    #pragma unroll
    for (int i=0;i<4;++i)
      #pragma unroll
      for (int j=0;j<4;++j){ double2 v = g_V[((k*4+i)*4+j)*F + f]; Vk[i][j] = mkcd(v.x, v.y); }
    cd M[4][4];
    #pragma unroll
    for (int i=0;i<4;++i)
      #pragma unroll
      for (int j=0;j<4;++j){
        cd s = mkcd(0.0,0.0);
        #pragma unroll
        for (int c=0;c<4;++c) s = cadd(s, cmul(W[i][c], Vk[c][j]));
        M[i][j] = s;
      }
    cd x[4]; x[0]=mkcd(0,0); x[1]=mkcd(0,0); x[2]=mkcd(0,0); x[3]=mkcd(0,0); x[k]=mkcd(1,0);
    solve4(M, x);                       // x = inv(M)[:,k]
    cd w[4];
    #pragma unroll
    for (int c=0;c<4;++c) w[c] = conj_(x[c]);
    double dre = 0.0;
    #pragma unroll
    for (int j=0;j<4;++j){
      cd tj = mkcd(0.0,0.0);
      #pragma unroll
      for (int c=0;c<4;++c) tj = cadd(tj, cmul(w[c], Vk[c][j]));
      cd z = cmul(tj, conj_(w[j]));
      dre += z.re;
    }
    double denom = sqrt(dre > 0.0 ? dre : 1e-300);
    #pragma unroll
    for (int c=0;c<4;++c) W[k][c] = mkcd(w[c].re/denom, w[c].im/denom);
  }
  #pragma unroll
  for (int s=0;s<4;++s)
    #pragma unroll
    for (int c=0;c<4;++c) g_Wh[f*16+s*4+c] = make_double2(W[s][c].re, W[s][c].im);
}

// scale[f,:] = inv(Wh[f])[:,0]
__global__ void scale_kernel(){
  int f = blockIdx.x*blockDim.x + threadIdx.x;
  if (f >= F) return;
  cd M[4][4];
  #pragma unroll
  for (int s=0;s<4;++s)
    #pragma unroll
    for (int c=0;c<4;++c){ double2 w = g_Wh[f*16+s*4+c]; M[s][c] = mkcd(w.x, w.y); }
  cd x[4]; x[0]=mkcd(1,0); x[1]=mkcd(0,0); x[2]=mkcd(0,0); x[3]=mkcd(0,0);
  solve4(M, x);
  #pragma unroll
  for (int s=0;s<4;++s) g_scale[f*4+s] = make_double2(x[s].re, x[s].im);
}

// out[s,f,b] = (Wh[f] X[:,f,b])[s] * scale[f,s]
// INTERLEAVED bf16 output: complex64.view(float32) order -> one (re,im) bf16 pair per element
__global__ __launch_bounds__(256) void final_kernel(
    const float* __restrict__ Xr, const float* __restrict__ Xi,
    __hip_bfloat162* __restrict__ out){
  int b = blockIdx.x*blockDim.x + threadIdx.x;
  if (b >= B) return;
  int f0 = blockIdx.y*FCH, f1 = min(f0+FCH, F);
  for (int f=f0; f<f1; ++f){
    double xr[K], xi[K];
    #pragma unroll
    for (int c=0;c<K;++c){ int idx=c*FB + f*B + b; xr[c]=(double)Xr[idx]; xi[c]=(double)Xi[idx]; }
    const double2* w = g_Wh + f*16;
    #pragma unroll
    for (int s=0;s<K;++s){
      double yr=0.0, yi=0.0;
      #pragma unroll
      for (int c=0;c<K;++c){
        double2 ww = w[s*4+c];
        yr += ww.x*xr[c] - ww.y*xi[c];
        yi += ww.x*xi[c] + ww.y*xr[c];
      }
      double2 sc = g_scale[f*4+s];
      float ore = (float)(yr*sc.x - yi*sc.y);
      float oim = (float)(yr*sc.y + yi*sc.x);
      __hip_bfloat162 o;
      o.x = __float2bfloat16(ore);
      o.y = __float2bfloat16(oim);
      out[s*FB + f*B + b] = o;
    }
  }
}

// ---------------- launch ----------------------------------------------------
extern "C" void kernel_launch(void* const* d_in, const int* in_sizes, int n_in,
                              void* d_out, int out_size, void* d_ws, size_t ws_size,
                              hipStream_t stream){
  // Inputs are passed ALPHABETIZED: d_in[0] = "Xi", d_in[1] = "Xr".
  // (Deduced: both natural layouts gave exactly the decorrelated |Re-Im| max
  //  statistic; X' = i*conj(X) commutes with the whole AuxIVA pipeline and
  //  swaps Re/Im of the output.)
  const float* Xr = (const float*)d_in[1];
  const float* Xi = (const float*)d_in[0];
  __hip_bfloat162* out = (__hip_bfloat162*)d_out;

  init_kernel<<<64, 256, 0, stream>>>();
  dim3 gD((B + 255)/256, NFC);
  dim3 gV(F, K);
  for (int it=0; it<NIT; ++it){
    demix_r2_kernel<<<gD, 256, 0, stream>>>(Xr, Xi);
    v_kernel<<<gV, 256, 0, stream>>>(Xr, Xi);
    update_kernel<<<8, 128, 0, stream>>>();
  }
  scale_kernel<<<(F + 63)/64, 64, 0, stream>>>();
  final_kernel<<<gD, 256, 0, stream>>>(Xr, Xi, out);
}

// Round 8
// 729.347 us; speedup vs baseline: 1.5867x; 1.5867x over previous
//
#include <hip/hip_runtime.h>
#include <hip/hip_bf16.h>
#include <math.h>

#define K 4
#define F 513
#define B 4000
#define NIT 5
#define FB (F*B)
#define FCH 8         // f-chunk for demix/final
#define NFC 65        // ceil(513/8)

// ---------------- persistent scratch: static device globals ------------------
__device__ float2 g_Wh[F*16];     // (F,4,4) complex fp32
__device__ float2 g_V[64*F];      // (k,i,j,f) complex fp32, k*16+i*4+j major
__device__ float2 g_scale[F*4];   // (F,4) complex fp32
__device__ float  g_r2[K*B];      // (K,B) real fp32

// ---------------- complex double helpers (tiny per-f solves only) -----------
struct cd { double re, im; };
__device__ inline cd mkcd(double r, double i){ cd z; z.re=r; z.im=i; return z; }
__device__ inline cd cmul(cd a, cd b){ return mkcd(a.re*b.re - a.im*b.im, a.re*b.im + a.im*b.re); }
__device__ inline cd cadd(cd a, cd b){ return mkcd(a.re+b.re, a.im+b.im); }
__device__ inline cd csub(cd a, cd b){ return mkcd(a.re-b.re, a.im-b.im); }
__device__ inline cd conj_(cd a){ return mkcd(a.re, -a.im); }
__device__ inline cd cdiv(cd a, cd b){
  double d = b.re*b.re + b.im*b.im;
  return mkcd((a.re*b.re + a.im*b.im)/d, (a.im*b.re - a.re*b.im)/d);
}

__device__ void solve4(cd M[4][4], cd x[4]){
  for (int col=0; col<4; ++col){
    int piv = col;
    double best = M[col][col].re*M[col][col].re + M[col][col].im*M[col][col].im;
    for (int r=col+1; r<4; ++r){
      double m = M[r][col].re*M[r][col].re + M[r][col].im*M[r][col].im;
      if (m > best){ best = m; piv = r; }
    }
    if (piv != col){
      for (int cc=0; cc<4; ++cc){ cd t=M[col][cc]; M[col][cc]=M[piv][cc]; M[piv][cc]=t; }
      cd t=x[col]; x[col]=x[piv]; x[piv]=t;
    }
    cd ip = cdiv(mkcd(1.0,0.0), M[col][col]);
    for (int cc=0; cc<4; ++cc) M[col][cc] = cmul(M[col][cc], ip);
    x[col] = cmul(x[col], ip);
    for (int r=0; r<4; ++r){
      if (r == col) continue;
      cd fct = M[r][col];
      for (int cc=0; cc<4; ++cc) M[r][cc] = csub(M[r][cc], cmul(fct, M[col][cc]));
      x[r] = csub(x[r], cmul(fct, x[col]));
    }
  }
}

// ---------------- kernels ---------------------------------------------------

__global__ void init_kernel(){
  int t = blockIdx.x*blockDim.x + threadIdx.x;
  if (t < F*16){
    int sc = t & 15; int s = sc >> 2, c = sc & 3;
    g_Wh[t] = make_float2(s==c ? 1.0f : 0.0f, 0.0f);
  }
  if (t < K*B) g_r2[t] = 0.0f;
}

// r2[k,b] += sum over this block's f-chunk of |Y[k,f,b]|^2, Y = Wh[f] * X[:,f,b]
__global__ __launch_bounds__(256) void demix_r2_kernel(
    const float* __restrict__ Xr, const float* __restrict__ Xi){
  int b = blockIdx.x*blockDim.x + threadIdx.x;
  if (b >= B) return;
  int f0 = blockIdx.y*FCH, f1 = min(f0+FCH, F);
  float acc[K];
  #pragma unroll
  for (int s=0;s<K;++s) acc[s]=0.0f;
  for (int f=f0; f<f1; ++f){
    float xr[K], xi[K];
    #pragma unroll
    for (int c=0;c<K;++c){ int idx=c*FB + f*B + b; xr[c]=Xr[idx]; xi[c]=Xi[idx]; }
    const float2* w = g_Wh + f*16;
    #pragma unroll
    for (int s=0;s<K;++s){
      float yr=0.0f, yi=0.0f;
      #pragma unroll
      for (int c=0;c<K;++c){
        float2 ww = w[s*4+c];
        yr += ww.x*xr[c] - ww.y*xi[c];
        yi += ww.x*xi[c] + ww.y*xr[c];
      }
      acc[s] += yr*yr + yi*yi;
    }
  }
  #pragma unroll
  for (int s=0;s<K;++s) atomicAdd(&g_r2[s*B+b], acc[s]);
}

// V[k,i,j,f] = (1/B) sum_b phi[k,b] X[i,f,b] conj(X[j,f,b]); one block per f, all k.
__global__ __launch_bounds__(256) void v_kernel(
    const float* __restrict__ Xr, const float* __restrict__ Xi){
  int f = blockIdx.x;
  int tid = threadIdx.x;
  float acc[64];
  #pragma unroll
  for (int q=0;q<64;++q) acc[q]=0.0f;

  for (int b=tid; b<B; b+=256){
    float phi[K];
    #pragma unroll
    for (int k=0;k<K;++k) phi[k] = 0.5f / sqrtf(g_r2[k*B+b]);
    float xr[K], xi[K];
    #pragma unroll
    for (int c=0;c<K;++c){ int idx=c*FB + f*B + b; xr[c]=Xr[idx]; xi[c]=Xi[idx]; }
    float p[16];
    #pragma unroll
    for (int i=0;i<4;++i) p[i] = xr[i]*xr[i] + xi[i]*xi[i];   // diagonals (real)
    int s = 4;
    #pragma unroll
    for (int i=0;i<4;++i){
      #pragma unroll
      for (int j=i+1;j<4;++j){
        p[s++] = xr[i]*xr[j] + xi[i]*xi[j];   // Re(X_i conj(X_j))
        p[s++] = xi[i]*xr[j] - xr[i]*xi[j];   // Im(X_i conj(X_j))
      }
    }
    #pragma unroll
    for (int k=0;k<K;++k){
      #pragma unroll
      for (int q=0;q<16;++q) acc[k*16+q] += phi[k]*p[q];
    }
  }

  __shared__ float part[4*64];
  __shared__ float red[64];
  int lane = tid & 63, wave = tid >> 6;
  #pragma unroll
  for (int q=0;q<64;++q){
    float v = acc[q];
    for (int off=32; off>0; off>>=1) v += __shfl_down(v, off);
    if (lane == 0) part[wave*64+q] = v;
  }
  __syncthreads();
  if (tid < 64){
    red[tid] = (part[tid] + part[64+tid] + part[128+tid] + part[192+tid]) * (1.0f/B);
  }
  __syncthreads();
  if (tid < 64){
    int k = tid >> 4, ij = tid & 15, i = ij >> 2, j = ij & 3;
    float re, im;
    if (i == j){ re = red[k*16 + i]; im = 0.0f; }
    else {
      int a = min(i,j), c2 = max(i,j);
      int pidx = (a==0) ? (c2-1) : ((a==1) ? (c2+1) : 5);
      re = red[k*16 + 4 + 2*pidx];
      im = red[k*16 + 5 + 2*pidx];
      if (i > j) im = -im;
    }
    g_V[(unsigned)tid*F + f] = make_float2(re, im);  // tid == k*16+i*4+j
  }
}

// Per-f IP updates k=0..3 (sequential), fp64 solves. Zeroes r2. Last iter: scale.
__global__ void update_kernel(int do_scale){
  int t = blockIdx.x*blockDim.x + threadIdx.x;
  int stride = gridDim.x*blockDim.x;
  for (int i=t; i<K*B; i+=stride) g_r2[i] = 0.0f;
  if (t >= F) return;
  int f = t;
  cd W[4][4];
  #pragma unroll
  for (int s=0;s<4;++s)
    #pragma unroll
    for (int c=0;c<4;++c){ float2 w = g_Wh[f*16+s*4+c]; W[s][c] = mkcd((double)w.x,(double)w.y); }

  for (int k=0;k<4;++k){
    cd Vk[4][4];
    #pragma unroll
    for (int i=0;i<4;++i)
      #pragma unroll
      for (int j=0;j<4;++j){ float2 v = g_V[((k*4+i)*4+j)*F + f]; Vk[i][j] = mkcd((double)v.x,(double)v.y); }
    cd M[4][4];
    #pragma unroll
    for (int i=0;i<4;++i)
      #pragma unroll
      for (int j=0;j<4;++j){
        cd s = mkcd(0.0,0.0);
        #pragma unroll
        for (int c=0;c<4;++c) s = cadd(s, cmul(W[i][c], Vk[c][j]));
        M[i][j] = s;
      }
    cd x[4]; x[0]=mkcd(0,0); x[1]=mkcd(0,0); x[2]=mkcd(0,0); x[3]=mkcd(0,0); x[k]=mkcd(1,0);
    solve4(M, x);                       // x = inv(M)[:,k]
    cd w[4];
    #pragma unroll
    for (int c=0;c<4;++c) w[c] = conj_(x[c]);
    double dre = 0.0;
    #pragma unroll
    for (int j=0;j<4;++j){
      cd tj = mkcd(0.0,0.0);
      #pragma unroll
      for (int c=0;c<4;++c) tj = cadd(tj, cmul(w[c], Vk[c][j]));
      cd z = cmul(tj, conj_(w[j]));
      dre += z.re;
    }
    double denom = sqrt(dre > 0.0 ? dre : 1e-300);
    #pragma unroll
    for (int c=0;c<4;++c) W[k][c] = mkcd(w[c].re/denom, w[c].im/denom);
  }
  #pragma unroll
  for (int s=0;s<4;++s)
    #pragma unroll
    for (int c=0;c<4;++c) g_Wh[f*16+s*4+c] = make_float2((float)W[s][c].re, (float)W[s][c].im);

  if (do_scale){
    cd M[4][4];
    #pragma unroll
    for (int s=0;s<4;++s)
      #pragma unroll
      for (int c=0;c<4;++c) M[s][c] = W[s][c];
    cd x[4]; x[0]=mkcd(1,0); x[1]=mkcd(0,0); x[2]=mkcd(0,0); x[3]=mkcd(0,0);
    solve4(M, x);   // x = inv(Wh)[:,0]
    #pragma unroll
    for (int s=0;s<4;++s) g_scale[f*4+s] = make_float2((float)x[s].re, (float)x[s].im);
  }
}

// out[s,f,b] = (Wh[f] X[:,f,b])[s] * scale[f,s]; interleaved (re,im) bf16 pairs
__global__ __launch_bounds__(256) void final_kernel(
    const float* __restrict__ Xr, const float* __restrict__ Xi,
    __hip_bfloat162* __restrict__ out){
  int b = blockIdx.x*blockDim.x + threadIdx.x;
  if (b >= B) return;
  int f0 = blockIdx.y*FCH, f1 = min(f0+FCH, F);
  for (int f=f0; f<f1; ++f){
    float xr[K], xi[K];
    #pragma unroll
    for (int c=0;c<K;++c){ int idx=c*FB + f*B + b; xr[c]=Xr[idx]; xi[c]=Xi[idx]; }
    const float2* w = g_Wh + f*16;
    #pragma unroll
    for (int s=0;s<K;++s){
      float yr=0.0f, yi=0.0f;
      #pragma unroll
      for (int c=0;c<K;++c){
        float2 ww = w[s*4+c];
        yr += ww.x*xr[c] - ww.y*xi[c];
        yi += ww.x*xi[c] + ww.y*xr[c];
      }
      float2 sc = g_scale[f*4+s];
      __hip_bfloat162 o;
      o.x = __float2bfloat16(yr*sc.x - yi*sc.y);
      o.y = __float2bfloat16(yr*sc.y + yi*sc.x);
      out[s*FB + f*B + b] = o;
    }
  }
}

// ---------------- launch ----------------------------------------------------
extern "C" void kernel_launch(void* const* d_in, const int* in_sizes, int n_in,
                              void* d_out, int out_size, void* d_ws, size_t ws_size,
                              hipStream_t stream){
  // Inputs arrive alphabetized: d_in[0]="Xi", d_in[1]="Xr" (verified round 7).
  const float* Xr = (const float*)d_in[1];
  const float* Xi = (const float*)d_in[0];
  __hip_bfloat162* out = (__hip_bfloat162*)d_out;

  init_kernel<<<64, 256, 0, stream>>>();
  dim3 gD((B + 255)/256, NFC);
  for (int it=0; it<NIT; ++it){
    demix_r2_kernel<<<gD, 256, 0, stream>>>(Xr, Xi);
    v_kernel<<<F, 256, 0, stream>>>(Xr, Xi);
    update_kernel<<<8, 128, 0, stream>>>(it == NIT-1 ? 1 : 0);
  }
  final_kernel<<<gD, 256, 0, stream>>>(Xr, Xi, out);
}

// Round 9
// 430.493 us; speedup vs baseline: 2.6881x; 1.6942x over previous
//
#include <hip/hip_runtime.h>
#include <hip/hip_bf16.h>
#include <math.h>

#define K 4
#define F 513
#define B 4000
#define NIT 5
#define FB (F*B)
#define KB (K*B)
#define FCH 8         // f-chunk for demix/final
#define NFC 65        // ceil(513/8)

// ---------------- persistent scratch: static device globals ------------------
__device__ float2 g_Wh[F*16];        // (F,4,4) complex fp32
__device__ float2 g_V[64*F];         // (k,i,j,f) complex fp32
__device__ float2 g_scale[F*4];      // (F,4) complex fp32
__device__ float  g_r2p[NFC*KB];     // per-chunk partials (plain stores, no init needed)
__device__ float  g_r2[KB];          // reduced (K,B)

// ---------------- complex double helpers (tiny per-f solves only) -----------
struct cd { double re, im; };
__device__ inline cd mkcd(double r, double i){ cd z; z.re=r; z.im=i; return z; }
__device__ inline cd cmul(cd a, cd b){ return mkcd(a.re*b.re - a.im*b.im, a.re*b.im + a.im*b.re); }
__device__ inline cd cadd(cd a, cd b){ return mkcd(a.re+b.re, a.im+b.im); }
__device__ inline cd csub(cd a, cd b){ return mkcd(a.re-b.re, a.im-b.im); }
__device__ inline cd conj_(cd a){ return mkcd(a.re, -a.im); }
__device__ inline cd cdiv(cd a, cd b){
  double d = b.re*b.re + b.im*b.im;
  return mkcd((a.re*b.re + a.im*b.im)/d, (a.im*b.re - a.re*b.im)/d);
}

// x = inv(M)[:,kk] via cofactors (branch-free, no pivoting).
// inv[i][kk] = (-1)^(kk+i) * minor_{kk,i} / det;  det = sum_i M[kk][i]*cof[i].
__device__ inline void invcol4(const cd M[4][4], int kk, cd x[4]){
  int r0 = (kk==0)?1:0;
  int r1 = (kk<=1)?2:1;
  int r2 = (kk<=2)?3:2;
  cd cof[4];
  #pragma unroll
  for (int i=0;i<4;++i){
    int c0 = (i==0)?1:0;
    int c1 = (i<=1)?2:1;
    int c2 = (i<=2)?3:2;
    cd m = cadd(csub(cmul(M[r0][c0], csub(cmul(M[r1][c1],M[r2][c2]), cmul(M[r1][c2],M[r2][c1]))),
                     cmul(M[r0][c1], csub(cmul(M[r1][c0],M[r2][c2]), cmul(M[r1][c2],M[r2][c0])))),
                cmul(M[r0][c2], csub(cmul(M[r1][c0],M[r2][c1]), cmul(M[r1][c1],M[r2][c0]))));
    if ((kk+i)&1) m = mkcd(-m.re,-m.im);
    cof[i] = m;
  }
  cd det = mkcd(0.0,0.0);
  #pragma unroll
  for (int i=0;i<4;++i) det = cadd(det, cmul(M[kk][i], cof[i]));
  cd idet = cdiv(mkcd(1.0,0.0), det);
  #pragma unroll
  for (int i=0;i<4;++i) x[i] = cmul(cof[i], idet);
}

// ---------------- kernels ---------------------------------------------------

__global__ void init_kernel(){
  int t = blockIdx.x*blockDim.x + threadIdx.x;
  if (t < F*16){
    int sc = t & 15; int s = sc >> 2, c = sc & 3;
    g_Wh[t] = make_float2(s==c ? 1.0f : 0.0f, 0.0f);
  }
}

// partial r2: r2p[y,k,b] = sum over f-chunk y of |(Wh[f] X[:,f,b])[k]|^2
__global__ __launch_bounds__(256) void demix_part_kernel(
    const float* __restrict__ Xr, const float* __restrict__ Xi){
  int b = blockIdx.x*blockDim.x + threadIdx.x;
  if (b >= B) return;
  int y = blockIdx.y;
  int f0 = y*FCH, f1 = min(f0+FCH, F);
  float acc[K];
  #pragma unroll
  for (int s=0;s<K;++s) acc[s]=0.0f;
  for (int f=f0; f<f1; ++f){
    float xr[K], xi[K];
    #pragma unroll
    for (int c=0;c<K;++c){ int idx=c*FB + f*B + b; xr[c]=Xr[idx]; xi[c]=Xi[idx]; }
    const float2* w = g_Wh + f*16;
    #pragma unroll
    for (int s=0;s<K;++s){
      float yr=0.0f, yi=0.0f;
      #pragma unroll
      for (int c=0;c<K;++c){
        float2 ww = w[s*4+c];
        yr += ww.x*xr[c] - ww.y*xi[c];
        yi += ww.x*xi[c] + ww.y*xr[c];
      }
      acc[s] += yr*yr + yi*yi;
    }
  }
  #pragma unroll
  for (int s=0;s<K;++s) g_r2p[y*KB + s*B + b] = acc[s];
}

// r2[k,b] = sum_y r2p[y,k,b]
__global__ __launch_bounds__(256) void reduce_r2_kernel(){
  int t = blockIdx.x*blockDim.x + threadIdx.x;
  if (t >= KB) return;
  float s = 0.0f;
  #pragma unroll 5
  for (int y=0; y<NFC; ++y) s += g_r2p[y*KB + t];
  g_r2[t] = s;
}

// V[k,i,j,f] = (1/B) sum_b phi[k,b] X[i,f,b] conj(X[j,f,b]); one block per f.
__global__ __launch_bounds__(256) void v_kernel(
    const float* __restrict__ Xr, const float* __restrict__ Xi){
  int f = blockIdx.x;
  int tid = threadIdx.x;
  float acc[64];
  #pragma unroll
  for (int q=0;q<64;++q) acc[q]=0.0f;

  for (int b=tid; b<B; b+=256){
    float phi[K];
    #pragma unroll
    for (int k=0;k<K;++k) phi[k] = 0.5f / sqrtf(g_r2[k*B+b]);
    float xr[K], xi[K];
    #pragma unroll
    for (int c=0;c<K;++c){ int idx=c*FB + f*B + b; xr[c]=Xr[idx]; xi[c]=Xi[idx]; }
    float p[16];
    #pragma unroll
    for (int i=0;i<4;++i) p[i] = xr[i]*xr[i] + xi[i]*xi[i];
    int s = 4;
    #pragma unroll
    for (int i=0;i<4;++i){
      #pragma unroll
      for (int j=i+1;j<4;++j){
        p[s++] = xr[i]*xr[j] + xi[i]*xi[j];
        p[s++] = xi[i]*xr[j] - xr[i]*xi[j];
      }
    }
    #pragma unroll
    for (int k=0;k<K;++k){
      #pragma unroll
      for (int q=0;q<16;++q) acc[k*16+q] += phi[k]*p[q];
    }
  }

  __shared__ float part[4*64];
  __shared__ float red[64];
  int lane = tid & 63, wave = tid >> 6;
  #pragma unroll
  for (int q=0;q<64;++q){
    float v = acc[q];
    for (int off=32; off>0; off>>=1) v += __shfl_down(v, off);
    if (lane == 0) part[wave*64+q] = v;
  }
  __syncthreads();
  if (tid < 64){
    red[tid] = (part[tid] + part[64+tid] + part[128+tid] + part[192+tid]) * (1.0f/B);
  }
  __syncthreads();
  if (tid < 64){
    int k = tid >> 4, ij = tid & 15, i = ij >> 2, j = ij & 3;
    float re, im;
    if (i == j){ re = red[k*16 + i]; im = 0.0f; }
    else {
      int a = min(i,j), c2 = max(i,j);
      int pidx = (a==0) ? (c2-1) : ((a==1) ? (c2+1) : 5);
      re = red[k*16 + 4 + 2*pidx];
      im = red[k*16 + 5 + 2*pidx];
      if (i > j) im = -im;
    }
    g_V[(unsigned)tid*F + f] = make_float2(re, im);
  }
}

// Per-f IP updates k=0..3 (sequential), fp64 cofactor solves, branch-free.
__global__ __launch_bounds__(64) void update_kernel(int do_scale){
  int f = blockIdx.x*blockDim.x + threadIdx.x;
  if (f >= F) return;
  cd W[4][4];
  #pragma unroll
  for (int s=0;s<4;++s)
    #pragma unroll
    for (int c=0;c<4;++c){ float2 w = g_Wh[f*16+s*4+c]; W[s][c] = mkcd((double)w.x,(double)w.y); }

  #pragma unroll
  for (int k=0;k<4;++k){
    cd Vk[4][4];
    #pragma unroll
    for (int i=0;i<4;++i)
      #pragma unroll
      for (int j=0;j<4;++j){ float2 v = g_V[((k*4+i)*4+j)*F + f]; Vk[i][j] = mkcd((double)v.x,(double)v.y); }
    cd M[4][4];
    #pragma unroll
    for (int i=0;i<4;++i)
      #pragma unroll
      for (int j=0;j<4;++j){
        cd s = mkcd(0.0,0.0);
        #pragma unroll
        for (int c=0;c<4;++c) s = cadd(s, cmul(W[i][c], Vk[c][j]));
        M[i][j] = s;
      }
    cd x[4];
    invcol4(M, k, x);                  // x = inv(M)[:,k]
    cd w[4];
    #pragma unroll
    for (int c=0;c<4;++c) w[c] = conj_(x[c]);
    double dre = 0.0;
    #pragma unroll
    for (int j=0;j<4;++j){
      cd tj = mkcd(0.0,0.0);
      #pragma unroll
      for (int c=0;c<4;++c) tj = cadd(tj, cmul(w[c], Vk[c][j]));
      dre += tj.re*w[j].re + tj.im*w[j].im;   // Re(tj * conj(w_j))
    }
    double inv_denom = rsqrt(dre > 0.0 ? dre : 1e-300);
    #pragma unroll
    for (int c=0;c<4;++c) W[k][c] = mkcd(w[c].re*inv_denom, w[c].im*inv_denom);
  }
  #pragma unroll
  for (int s=0;s<4;++s)
    #pragma unroll
    for (int c=0;c<4;++c) g_Wh[f*16+s*4+c] = make_float2((float)W[s][c].re, (float)W[s][c].im);

  if (do_scale){
    cd x[4];
    invcol4(W, 0, x);   // x = inv(Wh)[:,0]
    #pragma unroll
    for (int s=0;s<4;++s) g_scale[f*4+s] = make_float2((float)x[s].re, (float)x[s].im);
  }
}

// out[s,f,b] = (Wh[f] X[:,f,b])[s] * scale[f,s]; interleaved (re,im) bf16 pairs
__global__ __launch_bounds__(256) void final_kernel(
    const float* __restrict__ Xr, const float* __restrict__ Xi,
    __hip_bfloat162* __restrict__ out){
  int b = blockIdx.x*blockDim.x + threadIdx.x;
  if (b >= B) return;
  int f0 = blockIdx.y*FCH, f1 = min(f0+FCH, F);
  for (int f=f0; f<f1; ++f){
    float xr[K], xi[K];
    #pragma unroll
    for (int c=0;c<K;++c){ int idx=c*FB + f*B + b; xr[c]=Xr[idx]; xi[c]=Xi[idx]; }
    const float2* w = g_Wh + f*16;
    #pragma unroll
    for (int s=0;s<K;++s){
      float yr=0.0f, yi=0.0f;
      #pragma unroll
      for (int c=0;c<K;++c){
        float2 ww = w[s*4+c];
        yr += ww.x*xr[c] - ww.y*xi[c];
        yi += ww.x*xi[c] + ww.y*xr[c];
      }
      float2 sc = g_scale[f*4+s];
      __hip_bfloat162 o;
      o.x = __float2bfloat16(yr*sc.x - yi*sc.y);
      o.y = __float2bfloat16(yr*sc.y + yi*sc.x);
      out[s*FB + f*B + b] = o;
    }
  }
}

// ---------------- launch ----------------------------------------------------
extern "C" void kernel_launch(void* const* d_in, const int* in_sizes, int n_in,
                              void* d_out, int out_size, void* d_ws, size_t ws_size,
                              hipStream_t stream){
  // Inputs arrive alphabetized: d_in[0]="Xi", d_in[1]="Xr" (verified round 7).
  const float* Xr = (const float*)d_in[1];
  const float* Xi = (const float*)d_in[0];
  __hip_bfloat162* out = (__hip_bfloat162*)d_out;

  init_kernel<<<33, 256, 0, stream>>>();
  dim3 gD((B + 255)/256, NFC);
  for (int it=0; it<NIT; ++it){
    demix_part_kernel<<<gD, 256, 0, stream>>>(Xr, Xi);
    reduce_r2_kernel<<<(KB + 255)/256, 256, 0, stream>>>();
    v_kernel<<<F, 256, 0, stream>>>(Xr, Xi);
    update_kernel<<<(F + 63)/64, 64, 0, stream>>>(it == NIT-1 ? 1 : 0);
  }
  final_kernel<<<gD, 256, 0, stream>>>(Xr, Xi, out);
}